// Round 11
// baseline (71.053 us; speedup 1.0000x reference)
//
#include <hip/hip_runtime.h>
#include <math.h>

#define BB 16
#define NN 8400
#define CC 80
#define MM 64
#define KTOP 13
#define FEPS 1e-9f
#define CAP 2048   // per-(b,m) candidate capacity; theoretical max 1344
#define RPW 8      // u64 regs/lane for selection: RPW*256 == CAP

typedef float floatx4 __attribute__((ext_vector_type(4)));
typedef unsigned long long u64;

// ---- output layout (floats) ----
#define OFF_O1 134400
#define OFF_O2 672000
#define OFF_O3 11424000
#define OFF_O4 11558400

// ---- d_ws layout (ws_size = 256MB; we use ~18MB) ----
// ccnt  [1024 int]       at 0
// cntb  [134400 int]     at 1024
// mselb [134400 int]     at 135424
// aselb [134400 float]   at 269824
// cand  [1024*2048 u64]  at byte 1,616,896 (8B aligned)
#define ZERO_N (1024 + 3 * 134400)

__device__ __forceinline__ float iou_pair(const float4 g, const float4 p) {
    float ix1 = fmaxf(g.x, p.x);
    float iy1 = fmaxf(g.y, p.y);
    float ix2 = fminf(g.z, p.z);
    float iy2 = fminf(g.w, p.w);
    float iw = fmaxf(ix2 - ix1, 0.0f);
    float ih = fmaxf(iy2 - iy1, 0.0f);
    float inter = iw * ih;
    float aa = (g.z - g.x) * (g.w - g.y);
    float ab = (p.z - p.x) * (p.w - p.y);
    float uni = fmaxf(aa + ab - inter, FEPS);
    return inter / uni;
}

__global__ __launch_bounds__(256) void k_zero(int* __restrict__ p)
{
    int i = blockIdx.x * 256 + threadIdx.x;
    if (i < ZERO_N) p[i] = 0;
}

// Phase 1: block = 256 anchors of batch b. Pass A: in-box masks + slot
// reservation. Pass B: 8 subtiles x 32 anchors — stage score rows in LDS via
// COALESCED consecutive-float4 loads (streaming pattern class), then 8
// threads/anchor compute align for that anchor's hits from LDS and emit
// u64 composites (key<<32)|(NN-n) to per-(b,m) lists.
__global__ __launch_bounds__(256) void k_align_emit(
    const float* __restrict__ pd_scores, const float* __restrict__ pd_bboxes,
    const float* __restrict__ anc, const int* __restrict__ gt_labels,
    const float* __restrict__ gt_bboxes, const float* __restrict__ mask_gt,
    int* __restrict__ ccnt, u64* __restrict__ cand)
{
    const int b = blockIdx.y;
    const int tid = threadIdx.x;
    const int n0 = blockIdx.x * 256;
    const int n = n0 + tid;

    __shared__ float4 gtb[MM];
    __shared__ int    labS[MM];
    __shared__ int    hcnt[MM];
    __shared__ int    gbase[MM];
    __shared__ u64    maskS[256];
    __shared__ float4 srows4[640];   // 32 rows x 80 floats = 10KB
    __shared__ float4 pbbS[32];

    if (tid < MM) {
        float4 g = *(const float4*)&gt_bboxes[(size_t)(b * MM + tid) * 4];
        if (mask_gt[b * MM + tid] <= 0.5f)
            g = make_float4(1e30f, 1e30f, -1e30f, -1e30f);  // never hit
        gtb[tid] = g;
        int lb = gt_labels[b * MM + tid];
        labS[tid] = lb > 0 ? lb : 0;
        hcnt[tid] = 0;
    }
    __syncthreads();

    // pass A: in-box mask for own anchor
    float ax = 0.0f, ay = 0.0f;
    const bool inb = n < NN;
    if (inb) { float2 a2 = *(const float2*)&anc[2 * n]; ax = a2.x; ay = a2.y; }

    u64 mask = 0ull;
    #pragma unroll 8
    for (int m = 0; m < MM; ++m) {
        float4 g = gtb[m];
        float d1 = ax - g.x, d2 = ay - g.y, d3 = g.z - ax, d4 = g.w - ay;
        if (inb && fminf(fminf(d1, d2), fminf(d3, d4)) > FEPS)
            mask |= 1ull << m;
    }
    maskS[tid] = mask;

    // reserve per-(b,m) global ranges for this block
    u64 t = mask;
    while (t) { int m = __ffsll(t) - 1; t &= t - 1; atomicAdd(&hcnt[m], 1); }
    __syncthreads();
    if (tid < MM && hcnt[tid] > 0) {
        gbase[tid] = atomicAdd(&ccnt[b * MM + tid], hcnt[tid]);
        hcnt[tid] = 0;
    }

    // pass B: 8 subtiles of 32 anchors
    const float4* src4 = (const float4*)(pd_scores + (size_t)b * NN * CC);
    for (int sub = 0; sub < 8; ++sub) {
        const int la0 = sub * 32;          // local anchor base
        const int gn0 = n0 + la0;          // global anchor base
        __syncthreads();                   // srows reuse from prev subtile
        {
            const int base4 = gn0 * 20;    // float4 index of first row
            #pragma unroll
            for (int k = tid; k < 640; k += 256) {
                int gf = base4 + k;
                srows4[k] = (gf < NN * 20) ? src4[gf]
                                           : make_float4(0.f, 0.f, 0.f, 0.f);
            }
            if (tid < 32) {
                int gn = gn0 + tid;
                pbbS[tid] = (gn < NN)
                    ? *(const float4*)&pd_bboxes[((size_t)b * NN + gn) * 4]
                    : make_float4(0.f, 0.f, 0.f, 0.f);
            }
        }
        __syncthreads();

        // 8 threads per anchor: thread r handles bits m with m%8 == r
        const int la = la0 + (tid >> 3);
        const int r = tid & 7;
        u64 tt = maskS[la] & (0x0101010101010101ull << r);
        if (tt) {
            const float4 p = pbbS[la - la0];
            const float* row = (const float*)srows4 + (la - la0) * 80;
            const int gn = n0 + la;
            while (tt) {
                int m = __ffsll(tt) - 1; tt &= tt - 1;
                float io = iou_pair(gtb[m], p);
                float x = row[labS[m]];
                float s = 1.0f / (1.0f + expf(-x));
                float i2 = io * io;
                unsigned key = __float_as_uint(s * (i2 * i2 * i2));  // >= 0
                int slot = gbase[m] + atomicAdd(&hcnt[m], 1);
                if (slot < CAP)
                    cand[(size_t)(b * MM + m) * CAP + slot] =
                        ((u64)key << 32) | (unsigned)(NN - gn);
            }
        }
    }
}

// Phase 2: one workgroup per (b,m). Coalesced u64 candidate reads straight into
// registers, hierarchical 4-wave top-13 over unique composites, merge, emit.
__global__ __launch_bounds__(256) void k_topk(
    const int* __restrict__ ccnt, const u64* __restrict__ cand,
    int* __restrict__ cntb, int* __restrict__ mselb, float* __restrict__ aselb)
{
    const int bm = blockIdx.x;
    const int b = bm >> 6, m = bm & 63;
    const int tid = threadIdx.x;
    const int lane = tid & 63;
    const int wid = tid >> 6;

    __shared__ u64 cmerge[64];

    const unsigned epskey = __float_as_uint(FEPS);
    const int count = min(ccnt[bm], CAP);
    const u64* list = cand + (size_t)bm * CAP;

    u64 e[RPW];
    #pragma unroll
    for (int j = 0; j < RPW; ++j) {
        int i = tid + j * 256;
        e[j] = (i < count) ? list[i] : 0ull;   // coalesced
    }

    // stage A: per-wave top-13 of its subset, in registers
    {
        u64 lm = 0ull;
        #pragma unroll
        for (int j = 0; j < RPW; ++j) if (e[j] > lm) lm = e[j];

        u64 winv = 0ull;
        for (int r = 0; r < KTOP; ++r) {
            u64 bv = lm;
            #pragma unroll
            for (int off = 32; off > 0; off >>= 1) {
                u64 ov = __shfl_xor(bv, off, 64);
                if (ov > bv) bv = ov;
            }
            if ((unsigned)(bv >> 32) <= epskey) break;
            if (lane == r) winv = bv;
            if (lm == bv) {                    // unique -> exactly one lane
                #pragma unroll
                for (int j = 0; j < RPW; ++j) if (e[j] == bv) e[j] = 0ull;
                lm = 0ull;
                #pragma unroll
                for (int j = 0; j < RPW; ++j) if (e[j] > lm) lm = e[j];
            }
        }
        if (lane < KTOP) cmerge[wid * KTOP + lane] = winv;
        if (wid == 0 && lane >= 4 * KTOP) cmerge[lane] = 0ull;  // pad 52..63
    }
    __syncthreads();

    // stage B: wave 0 merges 52 candidates -> global top-13, emits positives
    if (wid == 0) {
        u64 v = cmerge[lane];
        u64 winv = 0ull;
        for (int r = 0; r < KTOP; ++r) {
            u64 bv = v;
            #pragma unroll
            for (int off = 32; off > 0; off >>= 1) {
                u64 ov = __shfl_xor(bv, off, 64);
                if (ov > bv) bv = ov;
            }
            if ((unsigned)(bv >> 32) <= epskey) break;
            if (lane == r) winv = bv;
            if (v == bv) v = 0ull;
        }
        if (lane < KTOP) {
            unsigned hk = (unsigned)(winv >> 32);
            if (hk > epskey) {     // positive floats: uint order == float order
                int n = NN - (int)(winv & 0xFFFFFFFFull);
                int ai = b * NN + n;
                atomicAdd(&cntb[ai], 1);
                atomicAdd(&mselb[ai], m);
                atomicAdd(&aselb[ai], __uint_as_float(hk));
            }
        }
    }
}

// Phase 3 (fused assign + cls): resolve per-anchor assignment, write
// out0/out1/out3/out4, then write this block's 256 cls rows (20 float4 each)
// coalesced + nontemporal from LDS-held labels/pers.
__global__ __launch_bounds__(256) void k_assign_cls(
    const float* __restrict__ pd_scores, const float* __restrict__ pd_bboxes,
    const float* __restrict__ anc, const int* __restrict__ gt_labels,
    const float* __restrict__ gt_bboxes, const float* __restrict__ mask_gt,
    const int* __restrict__ cntb, const int* __restrict__ mselb,
    const float* __restrict__ aselb,
    float* __restrict__ out0, float* __restrict__ out1,
    float* __restrict__ out3, float* __restrict__ out4,
    floatx4* __restrict__ cls4)
{
    const int b = blockIdx.y;
    const int n0 = blockIdx.x * 256;
    const int tid = threadIdx.x;
    const int n = n0 + tid;

    __shared__ float4 gtb[MM];
    __shared__ int    labS[MM];
    __shared__ float  mgS[MM];
    __shared__ int    labL[256];
    __shared__ float  perL[256];

    if (tid < MM) {
        int m = tid;
        gtb[m]  = *(const float4*)&gt_bboxes[(size_t)(b * MM + m) * 4];
        labS[m] = gt_labels[b * MM + m];
        mgS[m]  = mask_gt[b * MM + m];
    }
    __syncthreads();

    float per = 0.0f, fg = 0.0f;
    int mstar = 0;

    if (n < NN) {
        const size_t idx = (size_t)b * NN + n;
        const int cnt = cntb[idx];
        if (cnt > 0) {
            fg = 1.0f;
            const float4 p = *(const float4*)&pd_bboxes[idx * 4];
            if (cnt == 1) {
                mstar = mselb[idx];
                float a = aselb[idx];
                float io = iou_pair(gtb[mstar], p);   // positive => valid
                per = a / (a + FEPS) * io;
            } else {
                // multi-assigned: argmax IoU over valid m (first-max wins)
                float2 a2 = *(const float2*)&anc[2 * n];
                float bestI = -1.0f; int bestM = 0;
                for (int m = 0; m < MM; ++m) {
                    float4 gg = gtb[m];
                    float d1 = a2.x - gg.x, d2 = a2.y - gg.y;
                    float d3 = gg.z - a2.x, d4 = gg.w - a2.y;
                    bool valid = (fminf(fminf(d1, d2), fminf(d3, d4)) > FEPS) &&
                                 (mgS[m] > 0.5f);
                    float io = valid ? iou_pair(gg, p) : 0.0f;
                    if (io > bestI) { bestI = io; bestM = m; }
                }
                mstar = bestM;
                float io = bestI;
                int lb = labS[mstar]; int lbc = lb > 0 ? lb : 0;
                float x = pd_scores[idx * CC + lbc];
                float s = 1.0f / (1.0f + expf(-x));
                float i2 = io * io;
                float a = s * (i2 * i2 * i2);      // continuous-only recompute
                per = a / (a + FEPS) * io;
            }
        }
        out0[idx] = (float)labS[mstar];
        ((float4*)out1)[idx] = gtb[mstar];
        out3[idx] = fg;
        out4[idx] = (float)mstar;
    }
    labL[tid] = (n < NN) ? labS[mstar] : 0;
    perL[tid] = per;                           // 0 for invalid / background
    __syncthreads();

    // cls rows for this block's 256 anchors: 5120 float4s, coalesced
    const size_t base4 = ((size_t)b * NN + n0) * 20;
    for (int k = tid; k < 5120; k += 256) {
        int lrow = k / 20;
        int gn = n0 + lrow;
        if (gn >= NN) break;                   // uniform for the trailing block
        int c4 = (k - lrow * 20) * 4;
        int lab = labL[lrow];
        float pr = perL[lrow];
        int d = lab - c4;
        floatx4 v;
        v.x = (d == 0) ? pr : 0.0f;
        v.y = (d == 1) ? pr : 0.0f;
        v.z = (d == 2) ? pr : 0.0f;
        v.w = (d == 3) ? pr : 0.0f;
        __builtin_nontemporal_store(v, &cls4[base4 + k]);
    }
}

extern "C" void kernel_launch(void* const* d_in, const int* in_sizes, int n_in,
                              void* d_out, int out_size, void* d_ws, size_t ws_size,
                              hipStream_t stream) {
    const float* pd_scores = (const float*)d_in[0];
    const float* pd_bboxes = (const float*)d_in[1];
    const float* anc       = (const float*)d_in[2];
    const int*   gt_labels = (const int*)d_in[3];
    const float* gt_bboxes = (const float*)d_in[4];
    const float* mask_gt   = (const float*)d_in[5];

    float* out  = (float*)d_out;
    float* out0 = out;
    float* out1 = out + OFF_O1;
    float* out2 = out + OFF_O2;
    float* out3 = out + OFF_O3;
    float* out4 = out + OFF_O4;

    int*   ws_i  = (int*)d_ws;
    int*   ccnt  = ws_i;                        // 1024
    int*   cntb  = ws_i + 1024;                 // 134400
    int*   mselb = ws_i + 1024 + 134400;        // 134400
    float* aselb = (float*)(ws_i + 1024 + 2 * 134400);   // 134400
    u64*   cand  = (u64*)((char*)d_ws + (size_t)ZERO_N * 4);  // 16MB, 8B-aligned

    // 0) zero atomic scratch
    k_zero<<<dim3((ZERO_N + 255) / 256), dim3(256), 0, stream>>>(ws_i);

    // 1) in-box + LDS-staged streaming align + emit composites
    k_align_emit<<<dim3((NN + 255) / 256, BB), dim3(256), 0, stream>>>(
        pd_scores, pd_bboxes, anc, gt_labels, gt_bboxes, mask_gt, ccnt, cand);

    // 2) coalesced hierarchical register top-13 + emit positives
    k_topk<<<dim3(BB * MM), dim3(256), 0, stream>>>(
        ccnt, cand, cntb, mselb, aselb);

    // 3) per-anchor resolution + cls write (fused)
    k_assign_cls<<<dim3((NN + 255) / 256, BB), dim3(256), 0, stream>>>(
        pd_scores, pd_bboxes, anc, gt_labels, gt_bboxes, mask_gt,
        cntb, mselb, aselb, out0, out1, out3, out4, (floatx4*)out2);
}

// Round 12
// 61.788 us; speedup vs baseline: 1.1500x; 1.1500x over previous
//
#include <hip/hip_runtime.h>
#include <math.h>

#define BB 16
#define NN 8400
#define CC 80
#define MM 64
#define KTOP 13
#define FEPS 1e-9f
#define CAP 2048   // per-(b,m) candidate capacity; theoretical max 1344
#define RPW 8      // u64 regs/lane for selection: RPW*256 == CAP

typedef float floatx4 __attribute__((ext_vector_type(4)));
typedef unsigned long long u64;

// ---- output layout (floats) ----
#define OFF_O1 134400
#define OFF_O2 672000
#define OFF_O3 11424000
#define OFF_O4 11558400

// ---- d_ws layout ----
// ccnt [1024 int] | cntb [134400 int] | mselb [134400 int] | aselb [134400 f]
// cand [1024*2048 u64] after ZERO_N ints (8B aligned)
#define ZERO_N (1024 + 3 * 134400)

__device__ __forceinline__ float iou_pair(const float4 g, const float4 p) {
    float ix1 = fmaxf(g.x, p.x);
    float iy1 = fmaxf(g.y, p.y);
    float ix2 = fminf(g.z, p.z);
    float iy2 = fminf(g.w, p.w);
    float iw = fmaxf(ix2 - ix1, 0.0f);
    float ih = fmaxf(iy2 - iy1, 0.0f);
    float inter = iw * ih;
    float aa = (g.z - g.x) * (g.w - g.y);
    float ab = (p.z - p.x) * (p.w - p.y);
    float uni = fmaxf(aa + ab - inter, FEPS);
    return inter / uni;
}

__global__ __launch_bounds__(256) void k_zero(int* __restrict__ p)
{
    int i = blockIdx.x * 256 + threadIdx.x;
    if (i < ZERO_N) p[i] = 0;
}

// Phase 1: block = 64 anchors of batch b (grid 132 x 16 -> ~8 blocks/CU).
// Single stage/compute/emit chain, 3 barriers. Score rows staged via
// register-prefetch (loads in flight across pass A), then LDS.
// Pass A is atomic-free: thread (a,q) computes a u16 in-box piece for
// anchor a over gts q*16..q*16+15.
__global__ __launch_bounds__(256) void k_align_emit(
    const float* __restrict__ pd_scores, const float* __restrict__ pd_bboxes,
    const float* __restrict__ anc, const int* __restrict__ gt_labels,
    const float* __restrict__ gt_bboxes, const float* __restrict__ mask_gt,
    int* __restrict__ ccnt, u64* __restrict__ cand)
{
    const int b = blockIdx.y;
    const int n0 = blockIdx.x * 64;
    const int tid = threadIdx.x;
    const int a = tid >> 2;       // anchor 0..63
    const int q = tid & 3;        // gt-piece 0..3

    __shared__ float4 srows4[1280];        // 64 rows x 20 float4 = 20 KB
    __shared__ float4 gtb[MM];
    __shared__ float4 pbbS[64];
    __shared__ float2 ancS[64];
    __shared__ int    labS[MM];
    __shared__ unsigned short maskS16[256];
    __shared__ int hcnt[MM], hslot[MM], gbase[MM];

    // issue dense score stage loads into registers FIRST (fly across pass A)
    const float4* src4 = (const float4*)(pd_scores + (size_t)b * NN * CC);
    const int base4 = n0 * 20;
    const int lim = NN * 20 - base4;       // valid float4s in this window
    float4 r0 = (tid        < lim) ? src4[base4 + tid       ] : make_float4(0,0,0,0);
    float4 r1 = (tid + 256  < lim) ? src4[base4 + tid + 256 ] : make_float4(0,0,0,0);
    float4 r2 = (tid + 512  < lim) ? src4[base4 + tid + 512 ] : make_float4(0,0,0,0);
    float4 r3 = (tid + 768  < lim) ? src4[base4 + tid + 768 ] : make_float4(0,0,0,0);
    float4 r4 = (tid + 1024 < lim) ? src4[base4 + tid + 1024] : make_float4(0,0,0,0);

    if (tid < MM) {
        float4 g = *(const float4*)&gt_bboxes[(size_t)(b * MM + tid) * 4];
        if (mask_gt[b * MM + tid] <= 0.5f)
            g = make_float4(1e30f, 1e30f, -1e30f, -1e30f);  // never hit
        gtb[tid] = g;
        int lb = gt_labels[b * MM + tid];
        labS[tid] = lb > 0 ? lb : 0;
        hcnt[tid] = 0;
        hslot[tid] = 0;
    }
    if (tid < 64) {
        int gn = n0 + tid;
        pbbS[tid] = (gn < NN)
            ? *(const float4*)&pd_bboxes[((size_t)b * NN + gn) * 4]
            : make_float4(0.f, 0.f, 0.f, 0.f);
        ancS[tid] = (gn < NN) ? *(const float2*)&anc[2 * gn]
                              : make_float2(0.f, 0.f);
    }
    __syncthreads();

    // pass A: in-box u16 piece (atomic-free), overlaps the score loads
    {
        unsigned short pm = 0;
        if (n0 + a < NN) {
            float ax = ancS[a].x, ay = ancS[a].y;
            #pragma unroll
            for (int mm = 0; mm < 16; ++mm) {
                float4 g = gtb[q * 16 + mm];
                float d1 = ax - g.x, d2 = ay - g.y;
                float d3 = g.z - ax, d4 = g.w - ay;
                if (fminf(fminf(d1, d2), fminf(d3, d4)) > FEPS)
                    pm |= (unsigned short)(1u << mm);
            }
        }
        maskS16[tid] = pm;
        unsigned t16 = pm;
        while (t16) {                       // count hits (avg ~0.7/thread)
            int mm = __ffs(t16) - 1; t16 &= t16 - 1;
            atomicAdd(&hcnt[q * 16 + mm], 1);
        }
    }
    // now commit staged scores to LDS (waits for loads here)
    srows4[tid       ] = r0;
    srows4[tid + 256 ] = r1;
    srows4[tid + 512 ] = r2;
    srows4[tid + 768 ] = r3;
    srows4[tid + 1024] = r4;
    __syncthreads();

    if (tid < MM && hcnt[tid] > 0)
        gbase[tid] = atomicAdd(&ccnt[b * MM + tid], hcnt[tid]);
    __syncthreads();

    // emission: thread (a,q) walks its piece, computes align from LDS
    {
        unsigned t16 = maskS16[tid];
        if (t16) {
            const float4 p = pbbS[a];
            const float* row = (const float*)srows4 + a * 80;
            const int gn = n0 + a;
            while (t16) {
                int mm = __ffs(t16) - 1; t16 &= t16 - 1;
                int m = q * 16 + mm;
                float io = iou_pair(gtb[m], p);
                float x = row[labS[m]];
                float s = 1.0f / (1.0f + expf(-x));
                float i2 = io * io;
                unsigned key = __float_as_uint(s * (i2 * i2 * i2));  // >= 0
                int slot = gbase[m] + atomicAdd(&hslot[m], 1);
                if (slot < CAP)
                    cand[(size_t)(b * MM + m) * CAP + slot] =
                        ((u64)key << 32) | (unsigned)(NN - gn);
            }
        }
    }
}

// Phase 2: one workgroup per (b,m). Coalesced u64 candidate reads straight into
// registers, hierarchical 4-wave top-13 over unique composites, merge, emit.
__global__ __launch_bounds__(256) void k_topk(
    const int* __restrict__ ccnt, const u64* __restrict__ cand,
    int* __restrict__ cntb, int* __restrict__ mselb, float* __restrict__ aselb)
{
    const int bm = blockIdx.x;
    const int b = bm >> 6, m = bm & 63;
    const int tid = threadIdx.x;
    const int lane = tid & 63;
    const int wid = tid >> 6;

    __shared__ u64 cmerge[64];

    const unsigned epskey = __float_as_uint(FEPS);
    const int count = min(ccnt[bm], CAP);
    const u64* list = cand + (size_t)bm * CAP;

    u64 e[RPW];
    #pragma unroll
    for (int j = 0; j < RPW; ++j) {
        int i = tid + j * 256;
        e[j] = (i < count) ? list[i] : 0ull;   // coalesced
    }

    // stage A: per-wave top-13 of its subset, in registers
    {
        u64 lm = 0ull;
        #pragma unroll
        for (int j = 0; j < RPW; ++j) if (e[j] > lm) lm = e[j];

        u64 winv = 0ull;
        for (int r = 0; r < KTOP; ++r) {
            u64 bv = lm;
            #pragma unroll
            for (int off = 32; off > 0; off >>= 1) {
                u64 ov = __shfl_xor(bv, off, 64);
                if (ov > bv) bv = ov;
            }
            if ((unsigned)(bv >> 32) <= epskey) break;
            if (lane == r) winv = bv;
            if (lm == bv) {                    // unique -> exactly one lane
                #pragma unroll
                for (int j = 0; j < RPW; ++j) if (e[j] == bv) e[j] = 0ull;
                lm = 0ull;
                #pragma unroll
                for (int j = 0; j < RPW; ++j) if (e[j] > lm) lm = e[j];
            }
        }
        if (lane < KTOP) cmerge[wid * KTOP + lane] = winv;
        if (wid == 0 && lane >= 4 * KTOP) cmerge[lane] = 0ull;  // pad 52..63
    }
    __syncthreads();

    // stage B: wave 0 merges 52 candidates -> global top-13, emits positives
    if (wid == 0) {
        u64 v = cmerge[lane];
        u64 winv = 0ull;
        for (int r = 0; r < KTOP; ++r) {
            u64 bv = v;
            #pragma unroll
            for (int off = 32; off > 0; off >>= 1) {
                u64 ov = __shfl_xor(bv, off, 64);
                if (ov > bv) bv = ov;
            }
            if ((unsigned)(bv >> 32) <= epskey) break;
            if (lane == r) winv = bv;
            if (v == bv) v = 0ull;
        }
        if (lane < KTOP) {
            unsigned hk = (unsigned)(winv >> 32);
            if (hk > epskey) {     // positive floats: uint order == float order
                int n = NN - (int)(winv & 0xFFFFFFFFull);
                int ai = b * NN + n;
                atomicAdd(&cntb[ai], 1);
                atomicAdd(&mselb[ai], m);
                atomicAdd(&aselb[ai], __uint_as_float(hk));
            }
        }
    }
}

// Phase 3 (fused assign + cls): resolve per-anchor assignment, write
// out0/out1/out3/out4, then this block's 256 cls rows coalesced+nontemporal.
__global__ __launch_bounds__(256) void k_assign_cls(
    const float* __restrict__ pd_scores, const float* __restrict__ pd_bboxes,
    const float* __restrict__ anc, const int* __restrict__ gt_labels,
    const float* __restrict__ gt_bboxes, const float* __restrict__ mask_gt,
    const int* __restrict__ cntb, const int* __restrict__ mselb,
    const float* __restrict__ aselb,
    float* __restrict__ out0, float* __restrict__ out1,
    float* __restrict__ out3, float* __restrict__ out4,
    floatx4* __restrict__ cls4)
{
    const int b = blockIdx.y;
    const int n0 = blockIdx.x * 256;
    const int tid = threadIdx.x;
    const int n = n0 + tid;

    __shared__ float4 gtb[MM];
    __shared__ int    labS[MM];
    __shared__ float  mgS[MM];
    __shared__ int    labL[256];
    __shared__ float  perL[256];

    if (tid < MM) {
        int m = tid;
        gtb[m]  = *(const float4*)&gt_bboxes[(size_t)(b * MM + m) * 4];
        labS[m] = gt_labels[b * MM + m];
        mgS[m]  = mask_gt[b * MM + m];
    }
    __syncthreads();

    float per = 0.0f, fg = 0.0f;
    int mstar = 0;

    if (n < NN) {
        const size_t idx = (size_t)b * NN + n;
        const int cnt = cntb[idx];
        if (cnt > 0) {
            fg = 1.0f;
            const float4 p = *(const float4*)&pd_bboxes[idx * 4];
            if (cnt == 1) {
                mstar = mselb[idx];
                float a = aselb[idx];
                float io = iou_pair(gtb[mstar], p);   // positive => valid
                per = a / (a + FEPS) * io;
            } else {
                // multi-assigned: argmax IoU over valid m (first-max wins)
                float2 a2 = *(const float2*)&anc[2 * n];
                float bestI = -1.0f; int bestM = 0;
                for (int m = 0; m < MM; ++m) {
                    float4 gg = gtb[m];
                    float d1 = a2.x - gg.x, d2 = a2.y - gg.y;
                    float d3 = gg.z - a2.x, d4 = gg.w - a2.y;
                    bool valid = (fminf(fminf(d1, d2), fminf(d3, d4)) > FEPS) &&
                                 (mgS[m] > 0.5f);
                    float io = valid ? iou_pair(gg, p) : 0.0f;
                    if (io > bestI) { bestI = io; bestM = m; }
                }
                mstar = bestM;
                float io = bestI;
                int lb = labS[mstar]; int lbc = lb > 0 ? lb : 0;
                float x = pd_scores[idx * CC + lbc];
                float s = 1.0f / (1.0f + expf(-x));
                float i2 = io * io;
                float a = s * (i2 * i2 * i2);      // continuous-only recompute
                per = a / (a + FEPS) * io;
            }
        }
        out0[idx] = (float)labS[mstar];
        ((float4*)out1)[idx] = gtb[mstar];
        out3[idx] = fg;
        out4[idx] = (float)mstar;
    }
    labL[tid] = (n < NN) ? labS[mstar] : 0;
    perL[tid] = per;
    __syncthreads();

    // cls rows for this block's 256 anchors: 5120 float4s, coalesced
    const size_t base4 = ((size_t)b * NN + n0) * 20;
    for (int k = tid; k < 5120; k += 256) {
        int lrow = k / 20;
        int gn = n0 + lrow;
        if (gn >= NN) break;
        int c4 = (k - lrow * 20) * 4;
        int lab = labL[lrow];
        float pr = perL[lrow];
        int d = lab - c4;
        floatx4 v;
        v.x = (d == 0) ? pr : 0.0f;
        v.y = (d == 1) ? pr : 0.0f;
        v.z = (d == 2) ? pr : 0.0f;
        v.w = (d == 3) ? pr : 0.0f;
        __builtin_nontemporal_store(v, &cls4[base4 + k]);
    }
}

extern "C" void kernel_launch(void* const* d_in, const int* in_sizes, int n_in,
                              void* d_out, int out_size, void* d_ws, size_t ws_size,
                              hipStream_t stream) {
    const float* pd_scores = (const float*)d_in[0];
    const float* pd_bboxes = (const float*)d_in[1];
    const float* anc       = (const float*)d_in[2];
    const int*   gt_labels = (const int*)d_in[3];
    const float* gt_bboxes = (const float*)d_in[4];
    const float* mask_gt   = (const float*)d_in[5];

    float* out  = (float*)d_out;
    float* out0 = out;
    float* out1 = out + OFF_O1;
    float* out2 = out + OFF_O2;
    float* out3 = out + OFF_O3;
    float* out4 = out + OFF_O4;

    int*   ws_i  = (int*)d_ws;
    int*   ccnt  = ws_i;                        // 1024
    int*   cntb  = ws_i + 1024;                 // 134400
    int*   mselb = ws_i + 1024 + 134400;        // 134400
    float* aselb = (float*)(ws_i + 1024 + 2 * 134400);   // 134400
    u64*   cand  = (u64*)((char*)d_ws + (size_t)ZERO_N * 4);  // 16MB, 8B-aligned

    // 0) zero atomic scratch
    k_zero<<<dim3((ZERO_N + 255) / 256), dim3(256), 0, stream>>>(ws_i);

    // 1) 64-anchor blocks: prefetch-staged dense scores, in-box, emit
    k_align_emit<<<dim3((NN + 63) / 64, BB), dim3(256), 0, stream>>>(
        pd_scores, pd_bboxes, anc, gt_labels, gt_bboxes, mask_gt, ccnt, cand);

    // 2) coalesced hierarchical register top-13 + emit positives
    k_topk<<<dim3(BB * MM), dim3(256), 0, stream>>>(
        ccnt, cand, cntb, mselb, aselb);

    // 3) per-anchor resolution + cls write (fused)
    k_assign_cls<<<dim3((NN + 255) / 256, BB), dim3(256), 0, stream>>>(
        pd_scores, pd_bboxes, anc, gt_labels, gt_bboxes, mask_gt,
        cntb, mselb, aselb, out0, out1, out3, out4, (floatx4*)out2);
}